// Round 5
// baseline (744.128 us; speedup 1.0000x reference)
//
#include <hip/hip_runtime.h>

// DIAGNOSTIC BUILD (resubmit; r4 failed on container infra, not the kernel):
// r3 band-scatter kernel, but stores the (identical) output TWICE -- pass A
// with nontemporal float4 stores (== r3), pass B with plain stores --
// separated by a memory-clobber so neither pass is DSE'd. Purpose: push the
// blur dispatch above the ~335us harness fills so its FETCH_SIZE/WRITE_SIZE/
// VALUBusy/Occupancy become visible in top-5, and measure the marginal cost
// of a pure 533MB write pass.
// upfirdn2d UP=2, DOWN=1, KS=4, pad=(1,2). Input (16,128,128,128) f32 NCHW.

#define IH 128
#define IW 128

typedef float f2 __attribute__((ext_vector_type(2)));
typedef float f4 __attribute__((ext_vector_type(4)));
typedef f4 uf4 __attribute__((aligned(4)));   // ow=255 -> rows not 16B-aligned

__global__ __launch_bounds__(256) void blur_up2_diag(
    const float* __restrict__ in, const float* __restrict__ ker,
    float* __restrict__ out, int oh, int ow) {
    int bid = blockIdx.x;
    int lb  = (bid & 7) * (int)(gridDim.x >> 3) + (bid >> 3);
    int id  = lb * 256 + (int)threadIdx.x;

    int j    = id & 63;         // col-pair: ix = 2j, 2j+1
    int band = (id >> 6) & 31;  // input rows 4*band .. 4*band+4
    int nc   = id >> 11;        // n*C + c, 0..2047

    const float* ib = in + ((size_t)nc << 14) + (j << 1);
    int y0 = band << 2;
    bool jin = (j < 63);

    float A[5], B[5], E[5];
#pragma unroll
    for (int r = 0; r < 5; ++r) {
        int y = y0 + r;
        if (y < IH) {
            f2 v = *reinterpret_cast<const f2*>(ib + ((size_t)y << 7));
            A[r] = v.x; B[r] = v.y;
            E[r] = jin ? ib[((size_t)y << 7) + 2] : 0.f;
        } else {
            A[r] = 0.f; B[r] = 0.f; E[r] = 0.f;
        }
    }

    float K00 = ker[0],  K01 = ker[1],  K02 = ker[2],  K03 = ker[3];
    float K10 = ker[4],  K11 = ker[5],  K12 = ker[6],  K13 = ker[7];
    float K20 = ker[8],  K21 = ker[9],  K22 = ker[10], K23 = ker[11];
    float K30 = ker[12], K31 = ker[13], K32 = ker[14], K33 = ker[15];

    f4 O0[4], O1[4];
#pragma unroll
    for (int k = 0; k < 4; ++k) {
        float a = A[k],     b = B[k],     e = E[k];
        float c = A[k + 1], d = B[k + 1], f = E[k + 1];
        f4 o0, o1;
        o0.x = K11 * a + K13 * b + K31 * c + K33 * d;
        o0.y = K10 * a + K12 * b + K30 * c + K32 * d;
        o0.z = K11 * b + K13 * e + K31 * d + K33 * f;
        o0.w = K10 * b + K12 * e + K30 * d + K32 * f;
        o1.x = K01 * a + K03 * b + K21 * c + K23 * d;
        o1.y = K00 * a + K02 * b + K20 * c + K22 * d;
        o1.z = K01 * b + K03 * e + K21 * d + K23 * f;
        o1.w = K00 * b + K02 * e + K20 * d + K22 * f;
        O0[k] = o0; O1[k] = o1;
    }

    size_t obase = (size_t)nc * ((size_t)oh * ow);
    int ox  = j << 2;
    int rem = ow - ox;          // 3 for j=63, else >=4

    // ---- pass A: nontemporal stores (identical to r3) ----
#pragma unroll
    for (int k = 0; k < 4; ++k) {
        int oy = (y0 + k) << 1;
        size_t ob = obase + (size_t)oy * ow + ox;
        bool odd = (oy + 1 < oh);
        if (rem >= 4) {
            __builtin_nontemporal_store(O0[k], reinterpret_cast<uf4*>(out + ob));
            if (odd)
                __builtin_nontemporal_store(O1[k], reinterpret_cast<uf4*>(out + ob + ow));
        } else {
            out[ob] = O0[k].x; out[ob + 1] = O0[k].y; out[ob + 2] = O0[k].z;
            if (odd) {
                out[ob + ow] = O1[k].x; out[ob + ow + 1] = O1[k].y;
                out[ob + ow + 2] = O1[k].z;
            }
        }
    }

    asm volatile("" ::: "memory");   // keep both passes live

    // ---- pass B: plain stores (same values; marginal pure-write-pass cost) ----
#pragma unroll
    for (int k = 0; k < 4; ++k) {
        int oy = (y0 + k) << 1;
        size_t ob = obase + (size_t)oy * ow + ox;
        bool odd = (oy + 1 < oh);
        if (rem >= 4) {
            *reinterpret_cast<uf4*>(out + ob) = O0[k];
            if (odd) *reinterpret_cast<uf4*>(out + ob + ow) = O1[k];
        } else {
            out[ob] = O0[k].x; out[ob + 1] = O0[k].y; out[ob + 2] = O0[k].z;
            if (odd) {
                out[ob + ow] = O1[k].x; out[ob + ow + 1] = O1[k].y;
                out[ob + ow + 2] = O1[k].z;
            }
        }
    }
}

extern "C" void kernel_launch(void* const* d_in, const int* in_sizes, int n_in,
                              void* d_out, int out_size, void* d_ws, size_t ws_size,
                              hipStream_t stream) {
    const float* imgs = (const float*)d_in[0];
    const float* ker  = (const float*)d_in[1];
    float* out        = (float*)d_out;

    const int NC = 16 * 128;
    int ohw = out_size / NC;                     // OH*OW, square
    int ow = (ohw == 256 * 256) ? 256 : 255;     // hedge 255 vs 256
    int oh = ow;

    int total  = NC * 32 * 64;                   // 4,194,304 threads
    int blocks = total / 256;                    // 16,384
    blur_up2_diag<<<blocks, 256, 0, stream>>>(imgs, ker, out, oh, ow);
}